// Round 10
// baseline (76.199 us; speedup 1.0000x reference)
//
#include <hip/hip_runtime.h>
#include <stdint.h>

// LIF scan, chunk-parallel with warm-up convergence.
// v' = fma(v, 0.95, I); s = sigmoid(10(v'-1)); hard = v'>1; v'' = v'*(1-s)
// Outputs (f32, concat): spikes[B*L], hard_latency[B], soft_latency[B]
//
// R10: store-slack restructure. Single 64-row group per block, time-dbuf
//      (P=tile k, Q=tile k+1). Iter order: wait -> compute -> drain ->
//      stage(k+2). Drain stores are now OLDER than the next stage's loads,
//      so wait(k) targets stage(k) (issued iter k-2: full-iter load cover)
//      and stores get ~2 iterations of ack slack — R9's order made every
//      wait block on the previous drain's NT store retirement (~3000cyc,
//      0.75 iter slack) = the residual 70% stall. Grid 2048 -> 5 blocks/CU.

constexpr float TH_   = 1.0f;
constexpr float LEAK  = 0.95f;                   // 1 - 1/tau
constexpr float KL2E  = 14.426950408889634f;     // K * log2(e)
constexpr int   LDIM   = 4096;
constexpr int   TILE_T = 64;                     // timesteps per tile
constexpr int   CH     = TILE_T / 4;             // 16 float4 chunks per row
constexpr int   NCHUNK = 16;                     // time-parallel chunks
constexpr int   WARM   = 128;                    // warm-up steps

typedef __attribute__((address_space(1))) const unsigned int glob_u32;
typedef __attribute__((address_space(3))) unsigned int lds_u32;
typedef float __attribute__((ext_vector_type(4))) f32x4;   // NT-store-compatible

__device__ __forceinline__ float exp2_fast(float x) {
#if __has_builtin(__builtin_amdgcn_exp2f)
  return __builtin_amdgcn_exp2f(x);
#else
  return exp2f(x);
#endif
}

template <bool LAT>
__device__ __forceinline__ float lif_step(float& v, float Iv, float tf, float& latf) {
  v = fmaf(v, LEAK, Iv);                       // Euler, fused
  float e = exp2_fast(fmaf(-KL2E, v, KL2E));   // exp(-K*(v-TH)) in exp2 domain
  float s = __builtin_amdgcn_rcpf(1.0f + e);   // sigmoid
  if (LAT) {
    if (v > TH_) latf = fminf(latf, tf);       // first hard crossing (pre-reset v)
  }
  v = fmaf(-s, v, v);                          // v *= (1 - s)
  return s;
}

// ---- 64 rows x 64 cols tile, float4-chunk XOR swizzle (R4-proven) ----
// LDS: float4 buf[64*16]; linear slot (r*16+p) holds logical chunk p^(r&15).
// global_load_lds dest is lane-linear; per-lane GLOBAL src is pre-swizzled.

__device__ __forceinline__ void stage_tile(const float* __restrict__ I, float4* buf,
                                           int rowbase, int t0, int lane) {
  const int sub = lane >> 4;                   // 0..3
  const int p   = lane & 15;
#pragma unroll
  for (int i = 0; i < CH; ++i) {
    const int r = 4 * i + sub;
    const int c = p ^ (r & 15);
    const float* src = I + (size_t)(rowbase + r) * LDIM + t0 + 4 * c;
    __builtin_amdgcn_global_load_lds((glob_u32*)src, (lds_u32*)(buf + i * 64),
                                     16, 0, 0);   // 64 lanes x 16B -> 1KB slab
  }
}

__device__ __forceinline__ void drain_tile(const float4* buf, float* __restrict__ gOut,
                                           int lane) {
  const int c     = lane & 15;
  const int rbase = lane >> 4;
#pragma unroll
  for (int i = 0; i < CH; ++i) {
    const int r = 4 * i + rbase;
    float4 vd = buf[r * CH + (c ^ (r & 15))];  // swizzled ds_read_b128, conflict-free
    f32x4 w = {vd.x, vd.y, vd.z, vd.w};
    __builtin_nontemporal_store(w,
        reinterpret_cast<f32x4*>(gOut + (size_t)r * LDIM + 4 * c));  // 256B/row, NT
  }
}

// In-place: reads I chunk j+1 (prefetch), overwrites chunk j with S.
template <bool LAT>
__device__ __forceinline__ void process_tile(float4* __restrict__ buf, int lane,
                                             float& v, float& latf,
                                             float& ss, float& sst, float& tf) {
  const int m    = lane & 15;
  const int base = lane * CH;
  float4 c = buf[base + (0 ^ m)];
#pragma unroll
  for (int j = 0; j < CH; ++j) {
    float4 Ij = c;
    if (j + 1 < CH) c = buf[base + ((j + 1) ^ m)];
    float4 S;
    S.x = lif_step<LAT>(v, Ij.x, tf + 0.0f, latf);
    S.y = lif_step<LAT>(v, Ij.y, tf + 1.0f, latf);
    S.z = lif_step<LAT>(v, Ij.z, tf + 2.0f, latf);
    S.w = lif_step<LAT>(v, Ij.w, tf + 3.0f, latf);
    float g = (S.x + S.y) + (S.z + S.w);
    ss += g;
    sst = fmaf(g, tf, sst);
    sst += S.y;
    sst = fmaf(2.0f, S.z, sst);
    sst = fmaf(3.0f, S.w, sst);
    tf += 4.0f;
    buf[base + (j ^ m)] = S;                   // in-place S write
  }
}

__device__ __forceinline__ void warm_tile(const float4* __restrict__ buf, int lane,
                                          float& v) {
  const int m    = lane & 15;
  const int base = lane * CH;
  float dummy = 0.0f;
  float4 c = buf[base + (0 ^ m)];
#pragma unroll
  for (int j = 0; j < CH; ++j) {
    float4 Ij = c;
    if (j + 1 < CH) c = buf[base + ((j + 1) ^ m)];
    lif_step<false>(v, Ij.x, 0.0f, dummy);
    lif_step<false>(v, Ij.y, 0.0f, dummy);
    lif_step<false>(v, Ij.z, 0.0f, dummy);
    lif_step<false>(v, Ij.w, 0.0f, dummy);
  }
}

__device__ __forceinline__ void wait_vm(int n) {
  if (n >= 32)      asm volatile("s_waitcnt vmcnt(32)" ::: "memory");
  else if (n >= 16) asm volatile("s_waitcnt vmcnt(16)" ::: "memory");
  else              asm volatile("s_waitcnt vmcnt(0)"  ::: "memory");
}

template <bool DIRECT>
__global__ void __launch_bounds__(64) lif_scan(
    const float* __restrict__ I, float* __restrict__ spikes,
    float* __restrict__ pA, float* __restrict__ pB, float* __restrict__ pL,
    int B, int own, int warm) {
  __shared__ float4 lds[2][64 * CH];   // P/Q time-dbuf: 2 x 16 KiB

  const int lane  = threadIdx.x;
  const int row0  = blockIdx.x * 64;
  const int row   = row0 + lane;
  const int chunk = blockIdx.y;

  const int t_own = chunk * own;
  const int t_beg = (chunk == 0) ? 0 : t_own - warm;
  const int nwarm = (t_own - t_beg) / TILE_T;
  const int ntile = nwarm + own / TILE_T;

  float v = 0.0f;
  float latf = (float)LDIM;
  float ss = 0.0f, sst = 0.0f, tf = (float)t_own;

  // Prologue: stage tile 0 -> P, tile 1 -> Q.
  stage_tile(I, lds[0], row0, t_beg, lane);
  if (ntile > 1) stage_tile(I, lds[1], row0, t_beg + TILE_T, lane);

  for (int k = 0; k < ntile; ++k) {
    const int   t0       = t_beg + k * TILE_T;
    const bool  is_warm  = (k < nwarm);
    const bool  prev_own = (k > 0) && (k - 1 >= nwarm);
    const bool  has_ld   = (k + 1 < ntile);   // stage(k+1) loads were issued
    float4*     buf      = lds[k & 1];

    // wait: target = stage(k)'s 16 loads (issued at iter k-2 / prologue).
    // newer ops = drain(k-1) stores [16 if prev_own] + stage(k+1) loads
    // [16 if has_ld]. Stores older than stage(k) are from iter k-2 (~2 iters
    // of ack slack) — waits never block on a fresh drain.
    wait_vm((prev_own ? 16 : 0) + (has_ld ? 16 : 0));

    if (is_warm) {
      warm_tile(buf, lane, v);
    } else {
      if (!__all(latf < (float)LDIM))
        process_tile<true >(buf, lane, v, latf, ss, sst, tf);
      else
        process_tile<false>(buf, lane, v, latf, ss, sst, tf);
      drain_tile(buf, spikes + (size_t)row0 * LDIM + t0, lane);  // 16 NT stores
    }
    __builtin_amdgcn_sched_barrier(0);         // drain ds_reads precede restage
    if (k + 2 < ntile)
      stage_tile(I, buf, row0, t0 + 2 * TILE_T, lane);  // refill this buffer
  }

  if (DIRECT) {
    pL[row] = latf;
    pA[row] = sst / (ss + 1e-6f);
  } else {
    const size_t o = (size_t)chunk * B + row;
    pA[o] = ss;
    pB[o] = sst;
    pL[o] = latf;
  }
}

extern "C" __global__ void __launch_bounds__(256) lif_reduce(
    const float* __restrict__ pA, const float* __restrict__ pB,
    const float* __restrict__ pL, float* __restrict__ hard,
    float* __restrict__ soft, int B) {
  const int r = blockIdx.x * 256 + threadIdx.x;
  if (r >= B) return;
  float a = 0.0f, b = 0.0f, l = (float)LDIM;
  for (int c = 0; c < NCHUNK; ++c) {
    a += pA[(size_t)c * B + r];
    b += pB[(size_t)c * B + r];
    l = fminf(l, pL[(size_t)c * B + r]);
  }
  hard[r] = l;
  soft[r] = b / (a + 1e-6f);
}

extern "C" void kernel_launch(void* const* d_in, const int* in_sizes, int n_in,
                              void* d_out, int out_size, void* d_ws, size_t ws_size,
                              hipStream_t stream) {
  const float* I = (const float*)d_in[0];
  const int B = in_sizes[0] / LDIM;            // 8192
  float* out    = (float*)d_out;
  float* spikes = out;
  float* hard   = out + (size_t)B * LDIM;
  float* soft   = hard + B;

  const size_t need = (size_t)3 * NCHUNK * B * sizeof(float);
  if (ws_size >= need) {
    float* pA = (float*)d_ws;
    float* pB = pA + (size_t)NCHUNK * B;
    float* pL = pB + (size_t)NCHUNK * B;
    hipLaunchKernelGGL((lif_scan<false>), dim3(B / 64, NCHUNK), dim3(64), 0, stream,
                       I, spikes, pA, pB, pL, B, LDIM / NCHUNK, WARM);
    hipLaunchKernelGGL(lif_reduce, dim3((B + 255) / 256), dim3(256), 0, stream,
                       pA, pB, pL, hard, soft, B);
  } else {
    // fallback: single chunk, direct outputs (hard<-pL, soft<-pA)
    hipLaunchKernelGGL((lif_scan<true>), dim3(B / 64, 1), dim3(64), 0, stream,
                       I, spikes, soft, soft, hard, B, LDIM, 0);
  }
}

// Round 11
// 64.829 us; speedup vs baseline: 1.1754x; 1.1754x over previous
//
#include <hip/hip_runtime.h>
#include <stdint.h>

// LIF scan, chunk-parallel with warm-up convergence.
// v' = fma(v, 0.95, I); s = sigmoid(10(v'-1)); hard = v'>1; v'' = v'*(1-s)
// Outputs (f32, concat): spikes[B*L], hard_latency[B], soft_latency[B]
//
// R11: DRAM-granularity attack. All correct variants pin at ~62% of copy BW
//      with 256B segments @16KB stride (page-hit starved). TILE_T=128 makes
//      every load-slab and store 512B-contiguous per row (width-32 swizzle,
//      layout [64][32]xfloat4). Dist-2 time-dbuf (64KB LDS), NCHUNK=4 ->
//      grid 512 = 2 blocks/CU, ALL resident, single round (R9's lesson:
//      all-resident single-round beats more-but-ragged). Warm 33%->12%.

constexpr float TH_   = 1.0f;
constexpr float LEAK  = 0.95f;                   // 1 - 1/tau
constexpr float KL2E  = 14.426950408889634f;     // K * log2(e)
constexpr int   LDIM   = 4096;
constexpr int   TILE_T = 128;                    // timesteps per tile
constexpr int   CH     = TILE_T / 4;             // 32 float4 chunks per row
constexpr int   NCHUNK = 4;                      // time-parallel chunks
constexpr int   WARM   = 128;                    // warm-up steps (= 1 tile)

typedef __attribute__((address_space(1))) const unsigned int glob_u32;
typedef __attribute__((address_space(3))) unsigned int lds_u32;
typedef float __attribute__((ext_vector_type(4))) f32x4;   // NT-store-compatible

__device__ __forceinline__ float exp2_fast(float x) {
#if __has_builtin(__builtin_amdgcn_exp2f)
  return __builtin_amdgcn_exp2f(x);
#else
  return exp2f(x);
#endif
}

template <bool LAT>
__device__ __forceinline__ float lif_step(float& v, float Iv, float tf, float& latf) {
  v = fmaf(v, LEAK, Iv);                       // Euler, fused
  float e = exp2_fast(fmaf(-KL2E, v, KL2E));   // exp(-K*(v-TH)) in exp2 domain
  float s = __builtin_amdgcn_rcpf(1.0f + e);   // sigmoid
  if (LAT) {
    if (v > TH_) latf = fminf(latf, tf);       // first hard crossing (pre-reset v)
  }
  v = fmaf(-s, v, v);                          // v *= (1 - s)
  return s;
}

// ---- 64 rows x 128 cols tile, width-32 float4-chunk XOR swizzle ----
// LDS: float4 buf[64*32]; slot (r*32+p) holds logical chunk p^(r&31) of row r.
// Stage slab i (1KB, lane-linear dest) = rows {2i, 2i+1}: lanes 0..31 -> row
// 2i slots 0..31, lanes 32..63 -> row 2i+1. Pre-swizzled global source is
// 512B-contiguous per row (rule #21: linear dest + inverse-swizzled source).

__device__ __forceinline__ void stage_tile(const float* __restrict__ I, float4* buf,
                                           int rowbase, int t0, int lane) {
  const int rh = lane >> 5;                    // 0..1 (row within slab)
  const int p  = lane & 31;                    // slot position
#pragma unroll
  for (int i = 0; i < 32; ++i) {
    const int r = 2 * i + rh;
    const int c = p ^ (r & 31);                // logical chunk at position p
    const float* src = I + (size_t)(rowbase + r) * LDIM + t0 + 4 * c;
    __builtin_amdgcn_global_load_lds((glob_u32*)src, (lds_u32*)(buf + i * 64),
                                     16, 0, 0);   // 64 lanes x 16B -> 1KB slab
  }
}

// Drain: instr i covers rows {2i, 2i+1} x 32 chunks -> 2 x 512B NT stores.
__device__ __forceinline__ void drain_tile(const float4* buf, float* __restrict__ gOut,
                                           int lane) {
  const int c  = lane & 31;
  const int rh = lane >> 5;
#pragma unroll
  for (int i = 0; i < 32; ++i) {
    const int r = 2 * i + rh;
    float4 vd = buf[r * CH + (c ^ (r & 31))];  // swizzled ds_read_b128
    f32x4 w = {vd.x, vd.y, vd.z, vd.w};
    __builtin_nontemporal_store(w,
        reinterpret_cast<f32x4*>(gOut + (size_t)r * LDIM + 4 * c));  // 512B/row
  }
}

// In-place: reads I chunk j+1 (prefetch), overwrites chunk j with S.
template <bool LAT>
__device__ __forceinline__ void process_tile(float4* __restrict__ buf, int lane,
                                             float& v, float& latf,
                                             float& ss, float& sst, float& tf) {
  const int m    = lane & 31;
  const int base = lane * CH;
  float4 c = buf[base + (0 ^ m)];
#pragma unroll
  for (int j = 0; j < CH; ++j) {
    float4 Ij = c;
    if (j + 1 < CH) c = buf[base + ((j + 1) ^ m)];
    float4 S;
    S.x = lif_step<LAT>(v, Ij.x, tf + 0.0f, latf);
    S.y = lif_step<LAT>(v, Ij.y, tf + 1.0f, latf);
    S.z = lif_step<LAT>(v, Ij.z, tf + 2.0f, latf);
    S.w = lif_step<LAT>(v, Ij.w, tf + 3.0f, latf);
    float g = (S.x + S.y) + (S.z + S.w);
    ss += g;
    sst = fmaf(g, tf, sst);
    sst += S.y;
    sst = fmaf(2.0f, S.z, sst);
    sst = fmaf(3.0f, S.w, sst);
    tf += 4.0f;
    buf[base + (j ^ m)] = S;                   // in-place S write
  }
}

__device__ __forceinline__ void warm_tile(const float4* __restrict__ buf, int lane,
                                          float& v) {
  const int m    = lane & 31;
  const int base = lane * CH;
  float dummy = 0.0f;
  float4 c = buf[base + (0 ^ m)];
#pragma unroll
  for (int j = 0; j < CH; ++j) {
    float4 Ij = c;
    if (j + 1 < CH) c = buf[base + ((j + 1) ^ m)];
    lif_step<false>(v, Ij.x, 0.0f, dummy);
    lif_step<false>(v, Ij.y, 0.0f, dummy);
    lif_step<false>(v, Ij.z, 0.0f, dummy);
    lif_step<false>(v, Ij.w, 0.0f, dummy);
  }
}

__device__ __forceinline__ void wait_vm(int n) {
  // possible n: 0, 32, 64 (vmcnt is 6-bit -> cap 63; the 1-op over-wait
  // targets a store issued a full compute phase earlier -> free).
  if (n >= 64)      asm volatile("s_waitcnt vmcnt(63)" ::: "memory");
  else if (n >= 32) asm volatile("s_waitcnt vmcnt(32)" ::: "memory");
  else              asm volatile("s_waitcnt vmcnt(0)"  ::: "memory");
}

template <bool DIRECT>
__global__ void __launch_bounds__(64) lif_scan(
    const float* __restrict__ I, float* __restrict__ spikes,
    float* __restrict__ pA, float* __restrict__ pB, float* __restrict__ pL,
    int B, int own, int warm) {
  __shared__ float4 lds[2][64 * CH];   // P/Q time-dbuf: 2 x 32 KiB = 64 KiB

  const int lane  = threadIdx.x;
  const int row0  = blockIdx.x * 64;
  const int row   = row0 + lane;
  const int chunk = blockIdx.y;

  const int t_own = chunk * own;
  const int t_beg = (chunk == 0) ? 0 : t_own - warm;
  const int nwarm = (t_own - t_beg) / TILE_T;
  const int ntile = nwarm + own / TILE_T;

  float v = 0.0f;
  float latf = (float)LDIM;
  float ss = 0.0f, sst = 0.0f, tf = (float)t_own;

  // Prologue: stage tile 0 -> P, tile 1 -> Q.
  stage_tile(I, lds[0], row0, t_beg, lane);
  if (ntile > 1) stage_tile(I, lds[1], row0, t_beg + TILE_T, lane);

  for (int k = 0; k < ntile; ++k) {
    const int   t0       = t_beg + k * TILE_T;
    const bool  is_warm  = (k < nwarm);
    const bool  prev_own = (k > 0) && (k - 1 >= nwarm);
    const bool  has_ld   = (k + 1 < ntile);   // stage(k+1) already issued
    float4*     buf      = lds[k & 1];

    // wait target = stage(k)'s 32 loads (issued at iter k-2 / prologue:
    // a full iteration of compute cover). newer = drain(k-1) [32S if
    // prev_own] + stage(k+1) [32L if has_ld]. Stores older than the target
    // are from iter k-2 -> ~2 iterations of ack slack.
    wait_vm((prev_own ? 32 : 0) + (has_ld ? 32 : 0));

    if (is_warm) {
      warm_tile(buf, lane, v);
    } else {
      if (!__all(latf < (float)LDIM))
        process_tile<true >(buf, lane, v, latf, ss, sst, tf);
      else
        process_tile<false>(buf, lane, v, latf, ss, sst, tf);
      drain_tile(buf, spikes + (size_t)row0 * LDIM + t0, lane);  // 32 NT stores
    }
    __builtin_amdgcn_sched_barrier(0);         // drain ds_reads precede restage
    if (k + 2 < ntile)
      stage_tile(I, buf, row0, t0 + 2 * TILE_T, lane);  // refill this buffer
  }

  if (DIRECT) {
    pL[row] = latf;
    pA[row] = sst / (ss + 1e-6f);
  } else {
    const size_t o = (size_t)chunk * B + row;
    pA[o] = ss;
    pB[o] = sst;
    pL[o] = latf;
  }
}

extern "C" __global__ void __launch_bounds__(256) lif_reduce(
    const float* __restrict__ pA, const float* __restrict__ pB,
    const float* __restrict__ pL, float* __restrict__ hard,
    float* __restrict__ soft, int B) {
  const int r = blockIdx.x * 256 + threadIdx.x;
  if (r >= B) return;
  float a = 0.0f, b = 0.0f, l = (float)LDIM;
  for (int c = 0; c < NCHUNK; ++c) {
    a += pA[(size_t)c * B + r];
    b += pB[(size_t)c * B + r];
    l = fminf(l, pL[(size_t)c * B + r]);
  }
  hard[r] = l;
  soft[r] = b / (a + 1e-6f);
}

extern "C" void kernel_launch(void* const* d_in, const int* in_sizes, int n_in,
                              void* d_out, int out_size, void* d_ws, size_t ws_size,
                              hipStream_t stream) {
  const float* I = (const float*)d_in[0];
  const int B = in_sizes[0] / LDIM;            // 8192
  float* out    = (float*)d_out;
  float* spikes = out;
  float* hard   = out + (size_t)B * LDIM;
  float* soft   = hard + B;

  const size_t need = (size_t)3 * NCHUNK * B * sizeof(float);
  if (ws_size >= need) {
    float* pA = (float*)d_ws;
    float* pB = pA + (size_t)NCHUNK * B;
    float* pL = pB + (size_t)NCHUNK * B;
    hipLaunchKernelGGL((lif_scan<false>), dim3(B / 64, NCHUNK), dim3(64), 0, stream,
                       I, spikes, pA, pB, pL, B, LDIM / NCHUNK, WARM);
    hipLaunchKernelGGL(lif_reduce, dim3((B + 255) / 256), dim3(256), 0, stream,
                       pA, pB, pL, hard, soft, B);
  } else {
    // fallback: single chunk, direct outputs (hard<-pL, soft<-pA)
    hipLaunchKernelGGL((lif_scan<true>), dim3(B / 64, 1), dim3(64), 0, stream,
                       I, spikes, soft, soft, hard, B, LDIM, 0);
  }
}

// Round 12
// 59.320 us; speedup vs baseline: 1.2845x; 1.0929x over previous
//
#include <hip/hip_runtime.h>
#include <stdint.h>

// LIF scan, chunk-parallel with warm-up convergence.
// v' = fma(v, 0.95, I); s = sigmoid(10(v'-1)); hard = v'>1; v'' = v'*(1-s)
// Outputs (f32, concat): spikes[B*L], hard_latency[B], soft_latency[B]
//
// R12: R9 shell (2 row-groups/wave, 1024 blocks = 4/CU ALL-resident, 32KB
//      LDS, 64-step tiles, conflict-free swizzle) + reg-bounce drain:
//      ds_read S -> regs, lgkmcnt(0), stage refill loads, THEN NT stores.
//      Stores become the newest vmem ops -> waits (vmcnt 48) only block on
//      stores from 2 iterations back (~5000cyc ack slack). R9's
//      drain-before-stage order made every wait transitively block on the
//      previous drain's store retirement (<1 iter slack) — suspected cause
//      of the 91%-write-duty gap to the ~2.4 TB/s write-path wall.

constexpr float TH_   = 1.0f;
constexpr float LEAK  = 0.95f;                   // 1 - 1/tau
constexpr float KL2E  = 14.426950408889634f;     // K * log2(e)
constexpr int   LDIM   = 4096;
constexpr int   TILE_T = 64;                     // timesteps per tile
constexpr int   CH     = TILE_T / 4;             // 16 float4 chunks per row
constexpr int   NCHUNK = 16;                     // time-parallel chunks
constexpr int   WARM   = 128;                    // warm-up steps

typedef __attribute__((address_space(1))) const unsigned int glob_u32;
typedef __attribute__((address_space(3))) unsigned int lds_u32;
typedef float __attribute__((ext_vector_type(4))) f32x4;   // NT-store-compatible

__device__ __forceinline__ float exp2_fast(float x) {
#if __has_builtin(__builtin_amdgcn_exp2f)
  return __builtin_amdgcn_exp2f(x);
#else
  return exp2f(x);
#endif
}

template <bool LAT>
__device__ __forceinline__ float lif_step(float& v, float Iv, float tf, float& latf) {
  v = fmaf(v, LEAK, Iv);                       // Euler, fused
  float e = exp2_fast(fmaf(-KL2E, v, KL2E));   // exp(-K*(v-TH)) in exp2 domain
  float s = __builtin_amdgcn_rcpf(1.0f + e);   // sigmoid
  if (LAT) {
    if (v > TH_) latf = fminf(latf, tf);       // first hard crossing (pre-reset v)
  }
  v = fmaf(-s, v, v);                          // v *= (1 - s)
  return s;
}

// ---- 64 rows x 64 cols tile, float4-chunk XOR swizzle (R4-proven) ----
// LDS: float4 buf[64*16]; linear slot (r*16+p) holds logical chunk p^(r&15).
// global_load_lds dest is lane-linear; per-lane GLOBAL src is pre-swizzled.

__device__ __forceinline__ void stage_tile(const float* __restrict__ I, float4* buf,
                                           int rowbase, int t0, int lane) {
  const int sub = lane >> 4;                   // 0..3
  const int p   = lane & 15;
#pragma unroll
  for (int i = 0; i < CH; ++i) {
    const int r = 4 * i + sub;
    const int c = p ^ (r & 15);
    const float* src = I + (size_t)(rowbase + r) * LDIM + t0 + 4 * c;
    __builtin_amdgcn_global_load_lds((glob_u32*)src, (lds_u32*)(buf + i * 64),
                                     16, 0, 0);   // 64 lanes x 16B -> 1KB slab
  }
}

// Reg-bounce drain, part 1: swizzled ds_read_b128 of the S tile into regs.
__device__ __forceinline__ void read_tile_regs(const float4* buf, float4* d,
                                               int lane) {
  const int c     = lane & 15;
  const int rbase = lane >> 4;
#pragma unroll
  for (int i = 0; i < CH; ++i) {
    const int r = 4 * i + rbase;
    d[i] = buf[r * CH + (c ^ (r & 15))];       // conflict-free (2-way, free)
  }
}

// Reg-bounce drain, part 2: 16 NT stores, 256B contiguous per row-quad.
__device__ __forceinline__ void store_tile_regs(const float4* d,
                                                float* __restrict__ gOut, int lane) {
  const int c     = lane & 15;
  const int rbase = lane >> 4;
#pragma unroll
  for (int i = 0; i < CH; ++i) {
    const int r = 4 * i + rbase;
    f32x4 w = {d[i].x, d[i].y, d[i].z, d[i].w};
    __builtin_nontemporal_store(w,
        reinterpret_cast<f32x4*>(gOut + (size_t)r * LDIM + 4 * c));
  }
}

// In-place: reads I chunk j+1 (prefetch), overwrites chunk j with S.
template <bool LAT>
__device__ __forceinline__ void process_tile(float4* __restrict__ buf, int lane,
                                             float& v, float& latf,
                                             float& ss, float& sst, float& tf) {
  const int m    = lane & 15;
  const int base = lane * CH;
  float4 c = buf[base + (0 ^ m)];
#pragma unroll
  for (int j = 0; j < CH; ++j) {
    float4 Ij = c;
    if (j + 1 < CH) c = buf[base + ((j + 1) ^ m)];
    float4 S;
    S.x = lif_step<LAT>(v, Ij.x, tf + 0.0f, latf);
    S.y = lif_step<LAT>(v, Ij.y, tf + 1.0f, latf);
    S.z = lif_step<LAT>(v, Ij.z, tf + 2.0f, latf);
    S.w = lif_step<LAT>(v, Ij.w, tf + 3.0f, latf);
    float g = (S.x + S.y) + (S.z + S.w);
    ss += g;
    sst = fmaf(g, tf, sst);
    sst += S.y;
    sst = fmaf(2.0f, S.z, sst);
    sst = fmaf(3.0f, S.w, sst);
    tf += 4.0f;
    buf[base + (j ^ m)] = S;                   // in-place S write
  }
}

__device__ __forceinline__ void warm_tile(const float4* __restrict__ buf, int lane,
                                          float& v) {
  const int m    = lane & 15;
  const int base = lane * CH;
  float dummy = 0.0f;
  float4 c = buf[base + (0 ^ m)];
#pragma unroll
  for (int j = 0; j < CH; ++j) {
    float4 Ij = c;
    if (j + 1 < CH) c = buf[base + ((j + 1) ^ m)];
    lif_step<false>(v, Ij.x, 0.0f, dummy);
    lif_step<false>(v, Ij.y, 0.0f, dummy);
    lif_step<false>(v, Ij.z, 0.0f, dummy);
    lif_step<false>(v, Ij.w, 0.0f, dummy);
  }
}

__device__ __forceinline__ void wait_vm(int n) {
  if (n >= 48)      asm volatile("s_waitcnt vmcnt(48)" ::: "memory");
  else if (n >= 32) asm volatile("s_waitcnt vmcnt(32)" ::: "memory");
  else if (n >= 16) asm volatile("s_waitcnt vmcnt(16)" ::: "memory");
  else              asm volatile("s_waitcnt vmcnt(0)"  ::: "memory");
}

// Group phase: wait(exact) -> compute/warm -> [reads->regs, lgkm, stage, stores]
template <bool DIRECT>
__global__ void __launch_bounds__(64) lif_scan(
    const float* __restrict__ I, float* __restrict__ spikes,
    float* __restrict__ pA, float* __restrict__ pB, float* __restrict__ pL,
    int B, int own, int warm) {
  __shared__ float4 lds[2][64 * CH];   // A,B group tiles: 2 x 16 KiB

  const int lane  = threadIdx.x;
  const int row0  = blockIdx.x * 128;  // block covers 128 rows (2 groups of 64)
  const int chunk = blockIdx.y;

  const int t_own = chunk * own;
  const int t_beg = (chunk == 0) ? 0 : t_own - warm;
  const int nwarm = (t_own - t_beg) / TILE_T;
  const int ntile = nwarm + own / TILE_T;

  float vA = 0.0f, vB = 0.0f;
  float latA = (float)LDIM, latB = (float)LDIM;
  float ssA = 0.0f, sstA = 0.0f, tfA = (float)t_own;
  float ssB = 0.0f, sstB = 0.0f, tfB = (float)t_own;

  stage_tile(I, lds[0], row0,      t_beg, lane);
  stage_tile(I, lds[1], row0 + 64, t_beg, lane);

  for (int k = 0; k < ntile; ++k) {
    const int  t0       = t_beg + k * TILE_T;
    const bool is_warm  = (k < nwarm);
    const bool prev_own = (k > 0) && (k - 1 >= nwarm);
    const bool has_next = (k + 1 < ntile);

    // ---- group A ----
    // target stageA(k) [iter k-1 / prologue]; newer: storesA(k-1)[16 if
    // prev_own] + stageB(k)[16] + storesB(k-1)[16 if prev_own].
    wait_vm(16 + (prev_own ? 32 : 0));
    if (is_warm) {
      warm_tile(lds[0], lane, vA);
      __builtin_amdgcn_sched_barrier(0);
      if (has_next) stage_tile(I, lds[0], row0, t0 + TILE_T, lane);
    } else {
      if (!__all(latA < (float)LDIM))
        process_tile<true >(lds[0], lane, vA, latA, ssA, sstA, tfA);
      else
        process_tile<false>(lds[0], lane, vA, latA, ssA, sstA, tfA);
      float4 d[CH];
      read_tile_regs(lds[0], d, lane);                 // S tile -> regs
      asm volatile("s_waitcnt lgkmcnt(0)" ::: "memory");
      __builtin_amdgcn_sched_barrier(0);               // reads done before refill
      if (has_next) stage_tile(I, lds[0], row0, t0 + TILE_T, lane);
      __builtin_amdgcn_sched_barrier(0);               // loads issued before stores
      store_tile_regs(d, spikes + (size_t)row0 * LDIM + t0, lane);  // 16 NT st
    }

    // ---- group B ----
    // target stageB(k); newer: stageA(k+1)[16 if has_next] + storesA(k)[16 if
    // own] + storesB(k-1)[16 if prev_own].
    wait_vm((has_next ? 16 : 0) + (is_warm ? 0 : 16) + (prev_own ? 16 : 0));
    if (is_warm) {
      warm_tile(lds[1], lane, vB);
      __builtin_amdgcn_sched_barrier(0);
      if (has_next) stage_tile(I, lds[1], row0 + 64, t0 + TILE_T, lane);
    } else {
      if (!__all(latB < (float)LDIM))
        process_tile<true >(lds[1], lane, vB, latB, ssB, sstB, tfB);
      else
        process_tile<false>(lds[1], lane, vB, latB, ssB, sstB, tfB);
      float4 d[CH];
      read_tile_regs(lds[1], d, lane);
      asm volatile("s_waitcnt lgkmcnt(0)" ::: "memory");
      __builtin_amdgcn_sched_barrier(0);
      if (has_next) stage_tile(I, lds[1], row0 + 64, t0 + TILE_T, lane);
      __builtin_amdgcn_sched_barrier(0);
      store_tile_regs(d, spikes + (size_t)(row0 + 64) * LDIM + t0, lane);
    }
  }

  const int rowA = row0 + lane, rowB = row0 + 64 + lane;
  if (DIRECT) {
    pL[rowA] = latA;                 pL[rowB] = latB;
    pA[rowA] = sstA / (ssA + 1e-6f); pA[rowB] = sstB / (ssB + 1e-6f);
  } else {
    const size_t oA = (size_t)chunk * B + rowA;
    const size_t oB = (size_t)chunk * B + rowB;
    pA[oA] = ssA;  pB[oA] = sstA;  pL[oA] = latA;
    pA[oB] = ssB;  pB[oB] = sstB;  pL[oB] = latB;
  }
}

extern "C" __global__ void __launch_bounds__(256) lif_reduce(
    const float* __restrict__ pA, const float* __restrict__ pB,
    const float* __restrict__ pL, float* __restrict__ hard,
    float* __restrict__ soft, int B) {
  const int r = blockIdx.x * 256 + threadIdx.x;
  if (r >= B) return;
  float a = 0.0f, b = 0.0f, l = (float)LDIM;
  for (int c = 0; c < NCHUNK; ++c) {
    a += pA[(size_t)c * B + r];
    b += pB[(size_t)c * B + r];
    l = fminf(l, pL[(size_t)c * B + r]);
  }
  hard[r] = l;
  soft[r] = b / (a + 1e-6f);
}

extern "C" void kernel_launch(void* const* d_in, const int* in_sizes, int n_in,
                              void* d_out, int out_size, void* d_ws, size_t ws_size,
                              hipStream_t stream) {
  const float* I = (const float*)d_in[0];
  const int B = in_sizes[0] / LDIM;            // 8192
  float* out    = (float*)d_out;
  float* spikes = out;
  float* hard   = out + (size_t)B * LDIM;
  float* soft   = hard + B;

  const size_t need = (size_t)3 * NCHUNK * B * sizeof(float);
  if (ws_size >= need) {
    float* pA = (float*)d_ws;
    float* pB = pA + (size_t)NCHUNK * B;
    float* pL = pB + (size_t)NCHUNK * B;
    hipLaunchKernelGGL((lif_scan<false>), dim3(B / 128, NCHUNK), dim3(64), 0, stream,
                       I, spikes, pA, pB, pL, B, LDIM / NCHUNK, WARM);
    hipLaunchKernelGGL(lif_reduce, dim3((B + 255) / 256), dim3(256), 0, stream,
                       pA, pB, pL, hard, soft, B);
  } else {
    // fallback: single chunk, direct outputs (hard<-pL, soft<-pA)
    hipLaunchKernelGGL((lif_scan<true>), dim3(B / 128, 1), dim3(64), 0, stream,
                       I, spikes, soft, soft, hard, B, LDIM, 0);
  }
}

// Round 13
// 56.219 us; speedup vs baseline: 1.3554x; 1.0552x over previous
//
#include <hip/hip_runtime.h>
#include <stdint.h>

// LIF scan, chunk-parallel with warm-up convergence.
// v' = fma(v, 0.95, I); s = sigmoid(10(v'-1)); hard = v'>1; v'' = v'*(1-s)
// Outputs (f32, concat): spikes[B*L], hard_latency[B], soft_latency[B]
//
// R13: TLP x schedule, finally combined. Block = 256 threads = 4 INDEPENDENT
//      waves (no barriers); wave w owns rows [bx*256+64w, +64) and its own
//      16KB in-place LDS region. 64KB/block -> 2 blocks/CU = 8 waves/CU
//      (R12 had 4). Per-wave schedule = R12's reg-bounce ordering: wait ->
//      compute -> ds_read S->regs -> lgkm -> stage(k+1) -> NT stores(k).
//      Waits target stage(k) with stores one iteration slack (vmcnt 16/0).
//      512 blocks = 2/CU all-resident single round.

constexpr float TH_   = 1.0f;
constexpr float LEAK  = 0.95f;                   // 1 - 1/tau
constexpr float KL2E  = 14.426950408889634f;     // K * log2(e)
constexpr int   LDIM   = 4096;
constexpr int   TILE_T = 64;                     // timesteps per tile
constexpr int   CH     = TILE_T / 4;             // 16 float4 chunks per row
constexpr int   NCHUNK = 16;                     // time-parallel chunks
constexpr int   WARM   = 128;                    // warm-up steps

typedef __attribute__((address_space(1))) const unsigned int glob_u32;
typedef __attribute__((address_space(3))) unsigned int lds_u32;
typedef float __attribute__((ext_vector_type(4))) f32x4;   // NT-store-compatible

__device__ __forceinline__ float exp2_fast(float x) {
#if __has_builtin(__builtin_amdgcn_exp2f)
  return __builtin_amdgcn_exp2f(x);
#else
  return exp2f(x);
#endif
}

template <bool LAT>
__device__ __forceinline__ float lif_step(float& v, float Iv, float tf, float& latf) {
  v = fmaf(v, LEAK, Iv);                       // Euler, fused
  float e = exp2_fast(fmaf(-KL2E, v, KL2E));   // exp(-K*(v-TH)) in exp2 domain
  float s = __builtin_amdgcn_rcpf(1.0f + e);   // sigmoid
  if (LAT) {
    if (v > TH_) latf = fminf(latf, tf);       // first hard crossing (pre-reset v)
  }
  v = fmaf(-s, v, v);                          // v *= (1 - s)
  return s;
}

// ---- 64 rows x 64 cols tile, float4-chunk XOR swizzle (R4-proven) ----
// LDS: float4 buf[64*16]; linear slot (r*16+p) holds logical chunk p^(r&15).
// global_load_lds dest is lane-linear; per-lane GLOBAL src is pre-swizzled.

__device__ __forceinline__ void stage_tile(const float* __restrict__ I, float4* buf,
                                           int rowbase, int t0, int lane) {
  const int sub = lane >> 4;                   // 0..3
  const int p   = lane & 15;
#pragma unroll
  for (int i = 0; i < CH; ++i) {
    const int r = 4 * i + sub;
    const int c = p ^ (r & 15);
    const float* src = I + (size_t)(rowbase + r) * LDIM + t0 + 4 * c;
    __builtin_amdgcn_global_load_lds((glob_u32*)src, (lds_u32*)(buf + i * 64),
                                     16, 0, 0);   // 64 lanes x 16B -> 1KB slab
  }
}

// Reg-bounce drain, part 1: swizzled ds_read_b128 of the S tile into regs.
__device__ __forceinline__ void read_tile_regs(const float4* buf, float4* d,
                                               int lane) {
  const int c     = lane & 15;
  const int rbase = lane >> 4;
#pragma unroll
  for (int i = 0; i < CH; ++i) {
    const int r = 4 * i + rbase;
    d[i] = buf[r * CH + (c ^ (r & 15))];       // conflict-free (2-way, free)
  }
}

// Reg-bounce drain, part 2: 16 NT stores, 256B contiguous per row-quad.
__device__ __forceinline__ void store_tile_regs(const float4* d,
                                                float* __restrict__ gOut, int lane) {
  const int c     = lane & 15;
  const int rbase = lane >> 4;
#pragma unroll
  for (int i = 0; i < CH; ++i) {
    const int r = 4 * i + rbase;
    f32x4 w = {d[i].x, d[i].y, d[i].z, d[i].w};
    __builtin_nontemporal_store(w,
        reinterpret_cast<f32x4*>(gOut + (size_t)r * LDIM + 4 * c));
  }
}

// In-place: reads I chunk j+1 (prefetch), overwrites chunk j with S.
template <bool LAT>
__device__ __forceinline__ void process_tile(float4* __restrict__ buf, int lane,
                                             float& v, float& latf,
                                             float& ss, float& sst, float& tf) {
  const int m    = lane & 15;
  const int base = lane * CH;
  float4 c = buf[base + (0 ^ m)];
#pragma unroll
  for (int j = 0; j < CH; ++j) {
    float4 Ij = c;
    if (j + 1 < CH) c = buf[base + ((j + 1) ^ m)];
    float4 S;
    S.x = lif_step<LAT>(v, Ij.x, tf + 0.0f, latf);
    S.y = lif_step<LAT>(v, Ij.y, tf + 1.0f, latf);
    S.z = lif_step<LAT>(v, Ij.z, tf + 2.0f, latf);
    S.w = lif_step<LAT>(v, Ij.w, tf + 3.0f, latf);
    float g = (S.x + S.y) + (S.z + S.w);
    ss += g;
    sst = fmaf(g, tf, sst);
    sst += S.y;
    sst = fmaf(2.0f, S.z, sst);
    sst = fmaf(3.0f, S.w, sst);
    tf += 4.0f;
    buf[base + (j ^ m)] = S;                   // in-place S write
  }
}

__device__ __forceinline__ void warm_tile(const float4* __restrict__ buf, int lane,
                                          float& v) {
  const int m    = lane & 15;
  const int base = lane * CH;
  float dummy = 0.0f;
  float4 c = buf[base + (0 ^ m)];
#pragma unroll
  for (int j = 0; j < CH; ++j) {
    float4 Ij = c;
    if (j + 1 < CH) c = buf[base + ((j + 1) ^ m)];
    lif_step<false>(v, Ij.x, 0.0f, dummy);
    lif_step<false>(v, Ij.y, 0.0f, dummy);
    lif_step<false>(v, Ij.z, 0.0f, dummy);
    lif_step<false>(v, Ij.w, 0.0f, dummy);
  }
}

// Per-wave schedule; 4 independent waves per block (LDS-allocation trick).
template <bool DIRECT>
__global__ void __launch_bounds__(256) lif_scan(
    const float* __restrict__ I, float* __restrict__ spikes,
    float* __restrict__ pA, float* __restrict__ pB, float* __restrict__ pL,
    int B, int own, int warm) {
  __shared__ float4 lds[4][64 * CH];   // one 16 KiB in-place region per wave

  const int tid   = threadIdx.x;
  const int lane  = tid & 63;
  const int wid   = tid >> 6;          // 0..3
  const int row0  = blockIdx.x * 256 + wid * 64;
  const int row   = row0 + lane;
  const int chunk = blockIdx.y;
  float4*   buf   = lds[wid];

  const int t_own = chunk * own;
  const int t_beg = (chunk == 0) ? 0 : t_own - warm;
  const int nwarm = (t_own - t_beg) / TILE_T;
  const int ntile = nwarm + own / TILE_T;

  float v = 0.0f;
  float latf = (float)LDIM;
  float ss = 0.0f, sst = 0.0f, tf = (float)t_own;

  stage_tile(I, buf, row0, t_beg, lane);

  for (int k = 0; k < ntile; ++k) {
    const int  t0       = t_beg + k * TILE_T;
    const bool is_warm  = (k < nwarm);
    const bool prev_own = (k > 0) && (k - 1 >= nwarm);
    const bool has_next = (k + 1 < ntile);

    // wait: target = stage(k)'s 16 loads (issued end of iter k-1 / prologue).
    // newer = stores(k-1) [16 if prev_own] — issued AFTER stage(k), so
    // vmcnt(16) skips them. Stores(k-1) are only forced-retired at the top
    // of iter k+1 => one full iteration of ack slack.
    if (prev_own) asm volatile("s_waitcnt vmcnt(16)" ::: "memory");
    else          asm volatile("s_waitcnt vmcnt(0)"  ::: "memory");

    if (is_warm) {
      warm_tile(buf, lane, v);
      __builtin_amdgcn_sched_barrier(0);               // reads precede refill
      if (has_next) stage_tile(I, buf, row0, t0 + TILE_T, lane);
    } else {
      if (!__all(latf < (float)LDIM))
        process_tile<true >(buf, lane, v, latf, ss, sst, tf);
      else
        process_tile<false>(buf, lane, v, latf, ss, sst, tf);
      float4 d[CH];
      read_tile_regs(buf, d, lane);                    // S tile -> regs
      asm volatile("s_waitcnt lgkmcnt(0)" ::: "memory");
      __builtin_amdgcn_sched_barrier(0);               // reads done before refill
      if (has_next) stage_tile(I, buf, row0, t0 + TILE_T, lane);
      __builtin_amdgcn_sched_barrier(0);               // loads issued before stores
      store_tile_regs(d, spikes + (size_t)row0 * LDIM + t0, lane);  // 16 NT st
    }
  }

  if (DIRECT) {
    pL[row] = latf;
    pA[row] = sst / (ss + 1e-6f);
  } else {
    const size_t o = (size_t)chunk * B + row;
    pA[o] = ss;
    pB[o] = sst;
    pL[o] = latf;
  }
}

extern "C" __global__ void __launch_bounds__(256) lif_reduce(
    const float* __restrict__ pA, const float* __restrict__ pB,
    const float* __restrict__ pL, float* __restrict__ hard,
    float* __restrict__ soft, int B) {
  const int r = blockIdx.x * 256 + threadIdx.x;
  if (r >= B) return;
  float a = 0.0f, b = 0.0f, l = (float)LDIM;
  for (int c = 0; c < NCHUNK; ++c) {
    a += pA[(size_t)c * B + r];
    b += pB[(size_t)c * B + r];
    l = fminf(l, pL[(size_t)c * B + r]);
  }
  hard[r] = l;
  soft[r] = b / (a + 1e-6f);
}

extern "C" void kernel_launch(void* const* d_in, const int* in_sizes, int n_in,
                              void* d_out, int out_size, void* d_ws, size_t ws_size,
                              hipStream_t stream) {
  const float* I = (const float*)d_in[0];
  const int B = in_sizes[0] / LDIM;            // 8192
  float* out    = (float*)d_out;
  float* spikes = out;
  float* hard   = out + (size_t)B * LDIM;
  float* soft   = hard + B;

  const size_t need = (size_t)3 * NCHUNK * B * sizeof(float);
  if (ws_size >= need) {
    float* pA = (float*)d_ws;
    float* pB = pA + (size_t)NCHUNK * B;
    float* pL = pB + (size_t)NCHUNK * B;
    hipLaunchKernelGGL((lif_scan<false>), dim3(B / 256, NCHUNK), dim3(256), 0, stream,
                       I, spikes, pA, pB, pL, B, LDIM / NCHUNK, WARM);
    hipLaunchKernelGGL(lif_reduce, dim3((B + 255) / 256), dim3(256), 0, stream,
                       pA, pB, pL, hard, soft, B);
  } else {
    // fallback: single chunk, direct outputs (hard<-pL, soft<-pA)
    hipLaunchKernelGGL((lif_scan<true>), dim3(B / 256, 1), dim3(256), 0, stream,
                       I, spikes, soft, soft, hard, B, LDIM, 0);
  }
}